// Round 6
// baseline (1229.118 us; speedup 1.0000x reference)
//
#include <hip/hip_runtime.h>
#include <hip/hip_bf16.h>

#define NW 256
#define NDEPTH 10
#define NS 80           // shifts per matrix (sigma-grid resolution)
#define PIV_EPS 1e-6f   // LDL tiny-pivot guard

// float readlane broadcast (lane index compile-time in all uses)
__device__ __forceinline__ float rlf(float x, int lane) {
  return __int_as_float(__builtin_amdgcn_readlane(__float_as_int(x), lane));
}

// ---------------- fused forward: first fc + 10 residual blocks + last fc ----------------
__global__ __launch_bounds__(256) void forward_kernel(
    const float* __restrict__ x, const float* __restrict__ W1, const float* __restrict__ b1,
    const float* __restrict__ Wb, const float* __restrict__ bb,
    const float* __restrict__ Wl, const float* __restrict__ bl,
    float* __restrict__ out) {
  const int b = blockIdx.x;
  const int o = threadIdx.x;
  __shared__ __align__(16) float xs[784];
  __shared__ __align__(16) float ybuf[2][NW];

  for (int k = o; k < 784; k += 256) xs[k] = x[(size_t)b * 784 + k];
  __syncthreads();

  {
    const float* w1r = W1 + (size_t)o * 784;
    float s = b1[o];
    for (int k = 0; k < 784; k += 4) {
      float4 w = *(const float4*)(w1r + k);
      float4 xv = *(const float4*)(&xs[k]);
      s += w.x * xv.x + w.y * xv.y + w.z * xv.z + w.w * xv.w;
    }
    ybuf[0][o] = fmaxf(s, 0.f);
  }
  __syncthreads();

  int cur = 0;
  for (int d = 0; d < NDEPTH; ++d) {
    const float* wr = Wb + (size_t)d * NW * NW + (size_t)o * NW;
    const float* yc = ybuf[cur];
    float acc = bb[d * NW + o];
#pragma unroll 8
    for (int k = 0; k < NW; k += 4) {
      float4 w = *(const float4*)(wr + k);
      float4 yv = *(const float4*)(&yc[k]);
      acc += w.x * yv.x + w.y * yv.y + w.z * yv.z + w.w * yv.w;
    }
    float ynew = fmaxf(acc, 0.f) + yc[o];
    ybuf[cur ^ 1][o] = ynew;
    __syncthreads();
    cur ^= 1;
  }

  if (o < 10) {
    const float* wr = Wl + o * NW;
    const float* yc = ybuf[cur];
    float acc = bl[o];
    for (int k = 0; k < NW; k += 4) {
      float4 w = *(const float4*)(wr + k);
      float4 yv = *(const float4*)(&yc[k]);
      acc += w.x * yv.x + w.y * yv.y + w.z * yv.z + w.w * yv.w;
    }
    out[b * 10 + o] = acc;
  }
}

// ---------------- B = (I+W)^T (I+W) for all 10 blocks ----------------
__global__ void bmat_kernel(const float* __restrict__ Wb, float* __restrict__ Ball) {
  const int blk = blockIdx.x;        // 10 * 32
  const int k   = blk >> 5;
  const int r0  = (blk & 31) << 3;   // 8 rows per block
  const int c   = threadIdx.x;       // 256
  const float* W = Wb + (size_t)k * NW * NW;
  float acc[8] = {0.f,0.f,0.f,0.f,0.f,0.f,0.f,0.f};
  for (int j = 0; j < NW; ++j) {
    const float wc = W[j * NW + c];
#pragma unroll
    for (int rr = 0; rr < 8; ++rr) acc[rr] += wc * W[j * NW + r0 + rr];
  }
#pragma unroll
  for (int rr = 0; rr < 8; ++rr) {
    const int r = r0 + rr;
    float s = acc[rr] + W[c * NW + r] + W[r * NW + c] + ((r == c) ? 1.f : 0.f);
    Ball[(size_t)k * NW * NW + r * NW + c] = s;
  }
}

// ---------------- sigma upper bound per matrix: sqrt(max abs row sum) ----------------
__global__ void sighi_kernel(const float* __restrict__ Ball, float* __restrict__ sighi) {
  const int mat = blockIdx.x;       // 10
  const int t = threadIdx.x;        // 256 (one row each)
  const float* row = Ball + (size_t)mat * NW * NW + (size_t)t * NW;
  float s = 0.f;
  for (int c = 0; c < NW; c += 4) {
    const float4 v = *(const float4*)(row + c);
    s += fabsf(v.x) + fabsf(v.y) + fabsf(v.z) + fabsf(v.w);
  }
#pragma unroll
  for (int off = 32; off; off >>= 1) s = fmaxf(s, __shfl_down(s, off));
  __shared__ float wmax[4];
  if ((t & 63) == 0) wmax[t >> 6] = s;
  __syncthreads();
  if (t == 0)
    sighi[mat] = sqrtf(fmaxf(fmaxf(wmax[0], wmax[1]), fmaxf(wmax[2], wmax[3])));
}

// ---------------- LDL inertia kernel: one WG per (shift, matrix) ----------------
// counts[mat*NS + s] = #negative pivots of LDL^T(B - mu_s I) = #{lambda < mu_s}.
// Matrix in registers (thread t owns row r = ((t>>6)&3)*64 + lane, cols c0 = (t>>8)*64).
// vbuf double-buffered: read column k from vbuf[k&1], row-(k+1) owner dumps
// (by symmetry = column k+1) into vbuf[(k&1)^1]. One barrier per pivot step.
__global__ __launch_bounds__(1024, 1) void ldl_kernel(const float* __restrict__ Ball,
                                                      const float* __restrict__ sighi,
                                                      int* __restrict__ counts) {
  const int s   = blockIdx.x;     // shift index 0..NS-1
  const int mat = blockIdx.y;     // 0..9
  const int t = threadIdx.x;      // 0..1023
  const int l = t & 63;
  const int g = (t >> 6) & 3;
  const int q = t >> 8;
  const int r = (g << 6) + l;
  const int c0 = q << 6;
  const int gtop = (g << 6) + 63;

  __shared__ __align__(16) float vbuf[2][NW];

  const float h = sighi[mat] * (1.f / NS);
  const float sg = (s + 1) * h;
  const float mu = sg * sg;

  float Bv[64];
  {
    const float* src = Ball + (size_t)mat * NW * NW + (size_t)r * NW + c0;
#pragma unroll
    for (int gg = 0; gg < 16; ++gg) {
      const float4 f4 = *(const float4*)(src + 4 * gg);
      Bv[4*gg+0] = f4.x; Bv[4*gg+1] = f4.y; Bv[4*gg+2] = f4.z; Bv[4*gg+3] = f4.w;
    }
    // subtract mu on the diagonal (compile-time register indices)
#pragma unroll
    for (int jj = 0; jj < 64; ++jj)
      Bv[jj] -= (c0 + jj == r) ? mu : 0.f;
  }

  // initial dump: row 0 (= column 0 by symmetry)
  if (r == 0) {
#pragma unroll
    for (int gg = 0; gg < 16; ++gg)
      *(float4*)&vbuf[0][c0 + 4*gg] =
          make_float4(Bv[4*gg], Bv[4*gg+1], Bv[4*gg+2], Bv[4*gg+3]);
  }
  __syncthreads();

  int cnt = 0;
  for (int k = 0; k < NW; ++k) {
    const int par = k & 1;
    const float d = vbuf[par][k];          // pivot (uniform LDS broadcast)
    cnt += (d < 0.f) ? 1 : 0;
    if (gtop > k) {                        // wave has live rows
      const float dg = (fabsf(d) < PIV_EPS) ? copysignf(PIV_EPS, d) : d;
      const float dinv = __builtin_amdgcn_rcpf(dg);
      const float nf = (r > k) ? -vbuf[par][r] * dinv : 0.f;   // -L[r][k]
      const float vcl = vbuf[par][c0 + l];  // per-lane column value for broadcast
      // rank-1 update on live 16-col sub-blocks (dead elems updated harmlessly)
#pragma unroll
      for (int sb = 0; sb < 4; ++sb) {
        if (c0 + 16 * sb + 15 > k) {       // wave-uniform
#pragma unroll
          for (int jj = 0; jj < 16; ++jj) {
            const int j = 16 * sb + jj;
            Bv[j] = fmaf(nf, rlf(vcl, j), Bv[j]);
          }
        }
      }
      // row k+1 owner dumps updated row (= column k+1) into the other buffer
      if (r == k + 1) {
#pragma unroll
        for (int gg = 0; gg < 16; ++gg)
          *(float4*)&vbuf[par ^ 1][c0 + 4*gg] =
              make_float4(Bv[4*gg], Bv[4*gg+1], Bv[4*gg+2], Bv[4*gg+3]);
      }
    }
    __syncthreads();
  }

  if (t == 0) counts[mat * NS + s] = cnt;
}

// ---------------- gather: bin each sorted eigenvalue from inertia counts ----------------
__global__ void gather_kernel(const int* __restrict__ counts, const float* __restrict__ sighi,
                              float* __restrict__ sigw) {
  const int mat = blockIdx.x;   // 10
  const int j = threadIdx.x;    // 256, ascending eigenvalue index
  __shared__ int cs[NS];
  if (j < NS) cs[j] = counts[mat * NS + j];
  __syncthreads();
  const float h = sighi[mat] * (1.f / NS);
  int cmax = 0;
  int sstar = NS - 1;
  bool found = false;
  for (int s = 0; s < NS; ++s) {
    cmax = max(cmax, cs[s]);              // enforce monotone counts
    if (!found && cmax > j) { sstar = s; found = true; }
  }
  // lambda_j in [mu_{s*-1}, mu_{s*}) -> sigma in [s*h, (s*+1)h)
  sigw[mat * NW + (255 - j)] = (sstar + 0.5f) * h;   // descending order
}

// ---------------- mean over blocks, broadcast over batch ----------------
__global__ void sig_avg_kernel(const float* __restrict__ sig, float* __restrict__ out_all) {
  const int b = blockIdx.x;   // 256
  const int j = threadIdx.x;  // 256
  float s = 0.f;
#pragma unroll
  for (int k = 0; k < NDEPTH; ++k) s += sig[k * NW + j];
  out_all[b * NW + j] = s * 0.1f;
}

extern "C" void kernel_launch(void* const* d_in, const int* in_sizes, int n_in,
                              void* d_out, int out_size, void* d_ws, size_t ws_size,
                              hipStream_t stream) {
  const float* x  = (const float*)d_in[0];
  const float* W1 = (const float*)d_in[1];
  const float* b1 = (const float*)d_in[2];
  const float* Wb = (const float*)d_in[3];
  const float* bb = (const float*)d_in[4];
  const float* Wl = (const float*)d_in[5];
  const float* bl = (const float*)d_in[6];
  float* out = (float*)d_out;               // 2560 + 65536

  float* ws = (float*)d_ws;
  float* Ball   = ws;                       // 10*65536 = 655360 floats
  float* sigw   = ws + 655360;              // 2560 floats
  float* sighiW = ws + 657920;              // 10 floats
  int*   counts = (int*)(ws + 657936);      // 10*NS ints

  bmat_kernel<<<dim3(NDEPTH * 32), dim3(256), 0, stream>>>(Wb, Ball);
  sighi_kernel<<<dim3(NDEPTH), dim3(256), 0, stream>>>(Ball, sighiW);
  forward_kernel<<<dim3(256), dim3(256), 0, stream>>>(x, W1, b1, Wb, bb, Wl, bl, out);
  ldl_kernel<<<dim3(NS, NDEPTH), dim3(1024), 0, stream>>>(Ball, sighiW, counts);
  gather_kernel<<<dim3(NDEPTH), dim3(256), 0, stream>>>(counts, sighiW, sigw);
  sig_avg_kernel<<<dim3(256), dim3(256), 0, stream>>>(sigw, out + 2560);
}

// Round 7
// 1040.298 us; speedup vs baseline: 1.1815x; 1.1815x over previous
//
#include <hip/hip_runtime.h>
#include <hip/hip_bf16.h>

#define NW 256
#define NDEPTH 10
#define NS 80           // shifts per matrix (sigma-grid resolution)
#define PIV_EPS 1e-6f   // LDL tiny-pivot guard

// ---------------- fused forward: first fc + 10 residual blocks + last fc ----------------
__global__ __launch_bounds__(256) void forward_kernel(
    const float* __restrict__ x, const float* __restrict__ W1, const float* __restrict__ b1,
    const float* __restrict__ Wb, const float* __restrict__ bb,
    const float* __restrict__ Wl, const float* __restrict__ bl,
    float* __restrict__ out) {
  const int b = blockIdx.x;
  const int o = threadIdx.x;
  __shared__ __align__(16) float xs[784];
  __shared__ __align__(16) float ybuf[2][NW];

  for (int k = o; k < 784; k += 256) xs[k] = x[(size_t)b * 784 + k];
  __syncthreads();

  {
    const float* w1r = W1 + (size_t)o * 784;
    float s = b1[o];
    for (int k = 0; k < 784; k += 4) {
      float4 w = *(const float4*)(w1r + k);
      float4 xv = *(const float4*)(&xs[k]);
      s += w.x * xv.x + w.y * xv.y + w.z * xv.z + w.w * xv.w;
    }
    ybuf[0][o] = fmaxf(s, 0.f);
  }
  __syncthreads();

  int cur = 0;
  for (int d = 0; d < NDEPTH; ++d) {
    const float* wr = Wb + (size_t)d * NW * NW + (size_t)o * NW;
    const float* yc = ybuf[cur];
    float acc = bb[d * NW + o];
#pragma unroll 8
    for (int k = 0; k < NW; k += 4) {
      float4 w = *(const float4*)(wr + k);
      float4 yv = *(const float4*)(&yc[k]);
      acc += w.x * yv.x + w.y * yv.y + w.z * yv.z + w.w * yv.w;
    }
    float ynew = fmaxf(acc, 0.f) + yc[o];
    ybuf[cur ^ 1][o] = ynew;
    __syncthreads();
    cur ^= 1;
  }

  if (o < 10) {
    const float* wr = Wl + o * NW;
    const float* yc = ybuf[cur];
    float acc = bl[o];
    for (int k = 0; k < NW; k += 4) {
      float4 w = *(const float4*)(wr + k);
      float4 yv = *(const float4*)(&yc[k]);
      acc += w.x * yv.x + w.y * yv.y + w.z * yv.z + w.w * yv.w;
    }
    out[b * 10 + o] = acc;
  }
}

// ---------------- B = (I+W)^T (I+W) for all 10 blocks ----------------
__global__ void bmat_kernel(const float* __restrict__ Wb, float* __restrict__ Ball) {
  const int blk = blockIdx.x;        // 10 * 32
  const int k   = blk >> 5;
  const int r0  = (blk & 31) << 3;   // 8 rows per block
  const int c   = threadIdx.x;       // 256
  const float* W = Wb + (size_t)k * NW * NW;
  float acc[8] = {0.f,0.f,0.f,0.f,0.f,0.f,0.f,0.f};
  for (int j = 0; j < NW; ++j) {
    const float wc = W[j * NW + c];
#pragma unroll
    for (int rr = 0; rr < 8; ++rr) acc[rr] += wc * W[j * NW + r0 + rr];
  }
#pragma unroll
  for (int rr = 0; rr < 8; ++rr) {
    const int r = r0 + rr;
    float s = acc[rr] + W[c * NW + r] + W[r * NW + c] + ((r == c) ? 1.f : 0.f);
    Ball[(size_t)k * NW * NW + r * NW + c] = s;
  }
}

// ---------------- sigma upper bound per matrix: sqrt(max abs row sum) ----------------
__global__ void sighi_kernel(const float* __restrict__ Ball, float* __restrict__ sighi) {
  const int mat = blockIdx.x;       // 10
  const int t = threadIdx.x;        // 256 (one row each)
  const float* row = Ball + (size_t)mat * NW * NW + (size_t)t * NW;
  float s = 0.f;
  for (int c = 0; c < NW; c += 4) {
    const float4 v = *(const float4*)(row + c);
    s += fabsf(v.x) + fabsf(v.y) + fabsf(v.z) + fabsf(v.w);
  }
#pragma unroll
  for (int off = 32; off; off >>= 1) s = fmaxf(s, __shfl_down(s, off));
  __shared__ float wmax[4];
  if ((t & 63) == 0) wmax[t >> 6] = s;
  __syncthreads();
  if (t == 0)
    sighi[mat] = sqrtf(fmaxf(fmaxf(wmax[0], wmax[1]), fmaxf(wmax[2], wmax[3])));
}

// ---------------- LDL inertia kernel v2: 8x8 register tiles, no readlane ----------------
// counts[mat*NS + s] = #negative pivots of LDL^T(B - mu_s I) = #{lambda < mu_s}.
// Thread (rg = l&31, ch = 2w + (l>>5)) owns the 8x8 tile rows [8rg,8rg+8) x
// cols [8ch,8ch+8). Rank-1 update: 16 per-lane b128 operand loads per 64 FMAs.
// Wave w covers cols [16w,16w+16) -> column-death is wave-uniform (trim).
// vbuf double-buffered; dump of row k+1 (= column k+1 by symmetry) via a
// scalar-uniform switch so all register indices are compile-time.
__global__ __launch_bounds__(1024, 4) void ldl_kernel(const float* __restrict__ Ball,
                                                      const float* __restrict__ sighi,
                                                      int* __restrict__ counts) {
  const int s   = blockIdx.x;     // shift index 0..NS-1
  const int mat = blockIdx.y;     // 0..9
  const int t = threadIdx.x;      // 0..1023
  const int l = t & 63;
  const int w = t >> 6;              // wave 0..15
  const int rg = l & 31;             // row group: rows [8rg, 8rg+8)
  const int ch = 2 * w + (l >> 5);   // col chunk: cols [8ch, 8ch+8)
  const int r0 = rg << 3;
  const int c0 = ch << 3;

  __shared__ __align__(16) float vbuf[2][NW];

  const float h = sighi[mat] * (1.f / NS);
  const float sg = (s + 1) * h;
  const float mu = sg * sg;

  float4 Bq[16];   // Bq[2i], Bq[2i+1] = row r0+i, cols c0..c0+7
  {
    const float* src = Ball + (size_t)mat * NW * NW + (size_t)r0 * NW + c0;
#pragma unroll
    for (int i = 0; i < 8; ++i) {
      Bq[2*i]     = *(const float4*)(src + i * NW);
      Bq[2*i + 1] = *(const float4*)(src + i * NW + 4);
    }
  }
  // diagonal tile: subtract mu at (r0+i, c0+i)
  if (r0 == c0) {
    Bq[0].x  -= mu; Bq[2].y  -= mu; Bq[4].z  -= mu; Bq[6].w  -= mu;
    Bq[9].x  -= mu; Bq[11].y -= mu; Bq[13].z -= mu; Bq[15].w -= mu;
  }

  // initial dump: column 0 = row 0 (symmetry)
  if (rg == 0) {
    *(float4*)&vbuf[0][c0]     = Bq[0];
    *(float4*)&vbuf[0][c0 + 4] = Bq[1];
  }
  __syncthreads();

  int cnt = 0;
  for (int k = 0; k < NW; ++k) {
    const float* vb = vbuf[k & 1];
    const float d = vb[k];            // pivot (uniform broadcast read)
    cnt += (d < 0.f) ? 1 : 0;
    if (16 * w + 15 > k) {            // wave has live columns
      const float dg = (fabsf(d) < PIV_EPS) ? copysignf(PIV_EPS, d) : d;
      const float dinv = __builtin_amdgcn_rcpf(dg);
      const float4 cA = *(const float4*)&vb[c0];       // col values (per-lane)
      const float4 cB = *(const float4*)&vb[c0 + 4];
      const float4 rA = *(const float4*)&vb[r0];       // row values (per-lane)
      const float4 rB = *(const float4*)&vb[r0 + 4];
      const float rv[8] = {rA.x, rA.y, rA.z, rA.w, rB.x, rB.y, rB.z, rB.w};
      float f[8];
#pragma unroll
      for (int i = 0; i < 8; ++i)
        f[i] = (r0 + i > k) ? -rv[i] * dinv : 0.f;     // -L[r][k], masked rows
#pragma unroll
      for (int i = 0; i < 8; ++i) {
        Bq[2*i].x   = fmaf(f[i], cA.x, Bq[2*i].x);
        Bq[2*i].y   = fmaf(f[i], cA.y, Bq[2*i].y);
        Bq[2*i].z   = fmaf(f[i], cA.z, Bq[2*i].z);
        Bq[2*i].w   = fmaf(f[i], cA.w, Bq[2*i].w);
        Bq[2*i+1].x = fmaf(f[i], cB.x, Bq[2*i+1].x);
        Bq[2*i+1].y = fmaf(f[i], cB.y, Bq[2*i+1].y);
        Bq[2*i+1].z = fmaf(f[i], cB.z, Bq[2*i+1].z);
        Bq[2*i+1].w = fmaf(f[i], cB.w, Bq[2*i+1].w);
      }
      // dump updated row k+1 (= column k+1) into the other buffer.
      // (nr>>3, nr&7) -> owning row-group and tile-row; nr&7 is scalar-uniform.
      const int nr = k + 1;
      if (nr < NW && rg == (nr >> 3)) {
        float* vd = vbuf[nr & 1];
        switch (nr & 7) {
          case 0: *(float4*)&vd[c0] = Bq[0];  *(float4*)&vd[c0+4] = Bq[1];  break;
          case 1: *(float4*)&vd[c0] = Bq[2];  *(float4*)&vd[c0+4] = Bq[3];  break;
          case 2: *(float4*)&vd[c0] = Bq[4];  *(float4*)&vd[c0+4] = Bq[5];  break;
          case 3: *(float4*)&vd[c0] = Bq[6];  *(float4*)&vd[c0+4] = Bq[7];  break;
          case 4: *(float4*)&vd[c0] = Bq[8];  *(float4*)&vd[c0+4] = Bq[9];  break;
          case 5: *(float4*)&vd[c0] = Bq[10]; *(float4*)&vd[c0+4] = Bq[11]; break;
          case 6: *(float4*)&vd[c0] = Bq[12]; *(float4*)&vd[c0+4] = Bq[13]; break;
          case 7: *(float4*)&vd[c0] = Bq[14]; *(float4*)&vd[c0+4] = Bq[15]; break;
        }
      }
    }
    __syncthreads();
  }

  if (t == 0) counts[mat * NS + s] = cnt;
}

// ---------------- gather: bin each sorted eigenvalue from inertia counts ----------------
__global__ void gather_kernel(const int* __restrict__ counts, const float* __restrict__ sighi,
                              float* __restrict__ sigw) {
  const int mat = blockIdx.x;   // 10
  const int j = threadIdx.x;    // 256, ascending eigenvalue index
  __shared__ int cs[NS];
  if (j < NS) cs[j] = counts[mat * NS + j];
  __syncthreads();
  const float h = sighi[mat] * (1.f / NS);
  int cmax = 0;
  int sstar = NS - 1;
  bool found = false;
  for (int s = 0; s < NS; ++s) {
    cmax = max(cmax, cs[s]);              // enforce monotone counts
    if (!found && cmax > j) { sstar = s; found = true; }
  }
  // lambda_j in [mu_{s*-1}, mu_{s*}) -> sigma in [s*h, (s*+1)h)
  sigw[mat * NW + (255 - j)] = (sstar + 0.5f) * h;   // descending order
}

// ---------------- mean over blocks, broadcast over batch ----------------
__global__ void sig_avg_kernel(const float* __restrict__ sig, float* __restrict__ out_all) {
  const int b = blockIdx.x;   // 256
  const int j = threadIdx.x;  // 256
  float s = 0.f;
#pragma unroll
  for (int k = 0; k < NDEPTH; ++k) s += sig[k * NW + j];
  out_all[b * NW + j] = s * 0.1f;
}

extern "C" void kernel_launch(void* const* d_in, const int* in_sizes, int n_in,
                              void* d_out, int out_size, void* d_ws, size_t ws_size,
                              hipStream_t stream) {
  const float* x  = (const float*)d_in[0];
  const float* W1 = (const float*)d_in[1];
  const float* b1 = (const float*)d_in[2];
  const float* Wb = (const float*)d_in[3];
  const float* bb = (const float*)d_in[4];
  const float* Wl = (const float*)d_in[5];
  const float* bl = (const float*)d_in[6];
  float* out = (float*)d_out;               // 2560 + 65536

  float* ws = (float*)d_ws;
  float* Ball   = ws;                       // 10*65536 = 655360 floats
  float* sigw   = ws + 655360;              // 2560 floats
  float* sighiW = ws + 657920;              // 10 floats
  int*   counts = (int*)(ws + 657936);      // 10*NS ints

  bmat_kernel<<<dim3(NDEPTH * 32), dim3(256), 0, stream>>>(Wb, Ball);
  sighi_kernel<<<dim3(NDEPTH), dim3(256), 0, stream>>>(Ball, sighiW);
  forward_kernel<<<dim3(256), dim3(256), 0, stream>>>(x, W1, b1, Wb, bb, Wl, bl, out);
  ldl_kernel<<<dim3(NS, NDEPTH), dim3(1024), 0, stream>>>(Ball, sighiW, counts);
  gather_kernel<<<dim3(NDEPTH), dim3(256), 0, stream>>>(counts, sighiW, sigw);
  sig_avg_kernel<<<dim3(256), dim3(256), 0, stream>>>(sigw, out + 2560);
}

// Round 8
// 763.725 us; speedup vs baseline: 1.6094x; 1.3621x over previous
//
#include <hip/hip_runtime.h>
#include <hip/hip_bf16.h>

#define NW 256
#define NDEPTH 10
#define NS 76           // shifts per matrix (760 WGs ~ 3 rounds at 1 WG/CU)
#define PAD 10          // 8 floats padded to 10: gcd(10,32)=2 -> 2-way (free) conflicts
#define PIV_EPS 1e-6f   // LDL tiny-pivot guard

// ---------------- fused forward: first fc + 10 residual blocks + last fc ----------------
__global__ __launch_bounds__(256) void forward_kernel(
    const float* __restrict__ x, const float* __restrict__ W1, const float* __restrict__ b1,
    const float* __restrict__ Wb, const float* __restrict__ bb,
    const float* __restrict__ Wl, const float* __restrict__ bl,
    float* __restrict__ out) {
  const int b = blockIdx.x;
  const int o = threadIdx.x;
  __shared__ __align__(16) float xs[784];
  __shared__ __align__(16) float ybuf[2][NW];

  for (int k = o; k < 784; k += 256) xs[k] = x[(size_t)b * 784 + k];
  __syncthreads();

  {
    const float* w1r = W1 + (size_t)o * 784;
    float s = b1[o];
    for (int k = 0; k < 784; k += 4) {
      float4 w = *(const float4*)(w1r + k);
      float4 xv = *(const float4*)(&xs[k]);
      s += w.x * xv.x + w.y * xv.y + w.z * xv.z + w.w * xv.w;
    }
    ybuf[0][o] = fmaxf(s, 0.f);
  }
  __syncthreads();

  int cur = 0;
  for (int d = 0; d < NDEPTH; ++d) {
    const float* wr = Wb + (size_t)d * NW * NW + (size_t)o * NW;
    const float* yc = ybuf[cur];
    float acc = bb[d * NW + o];
#pragma unroll 8
    for (int k = 0; k < NW; k += 4) {
      float4 w = *(const float4*)(wr + k);
      float4 yv = *(const float4*)(&yc[k]);
      acc += w.x * yv.x + w.y * yv.y + w.z * yv.z + w.w * yv.w;
    }
    float ynew = fmaxf(acc, 0.f) + yc[o];
    ybuf[cur ^ 1][o] = ynew;
    __syncthreads();
    cur ^= 1;
  }

  if (o < 10) {
    const float* wr = Wl + o * NW;
    const float* yc = ybuf[cur];
    float acc = bl[o];
    for (int k = 0; k < NW; k += 4) {
      float4 w = *(const float4*)(wr + k);
      float4 yv = *(const float4*)(&yc[k]);
      acc += w.x * yv.x + w.y * yv.y + w.z * yv.z + w.w * yv.w;
    }
    out[b * 10 + o] = acc;
  }
}

// ---------------- B = (I+W)^T (I+W) for all 10 blocks ----------------
__global__ void bmat_kernel(const float* __restrict__ Wb, float* __restrict__ Ball) {
  const int blk = blockIdx.x;        // 10 * 32
  const int k   = blk >> 5;
  const int r0  = (blk & 31) << 3;   // 8 rows per block
  const int c   = threadIdx.x;       // 256
  const float* W = Wb + (size_t)k * NW * NW;
  float acc[8] = {0.f,0.f,0.f,0.f,0.f,0.f,0.f,0.f};
  for (int j = 0; j < NW; ++j) {
    const float wc = W[j * NW + c];
#pragma unroll
    for (int rr = 0; rr < 8; ++rr) acc[rr] += wc * W[j * NW + r0 + rr];
  }
#pragma unroll
  for (int rr = 0; rr < 8; ++rr) {
    const int r = r0 + rr;
    float s = acc[rr] + W[c * NW + r] + W[r * NW + c] + ((r == c) ? 1.f : 0.f);
    Ball[(size_t)k * NW * NW + r * NW + c] = s;
  }
}

// ---------------- sigma upper bound per matrix: sqrt(max abs row sum) ----------------
__global__ void sighi_kernel(const float* __restrict__ Ball, float* __restrict__ sighi) {
  const int mat = blockIdx.x;       // 10
  const int t = threadIdx.x;        // 256 (one row each)
  const float* row = Ball + (size_t)mat * NW * NW + (size_t)t * NW;
  float s = 0.f;
  for (int c = 0; c < NW; c += 4) {
    const float4 v = *(const float4*)(row + c);
    s += fabsf(v.x) + fabsf(v.y) + fabsf(v.z) + fabsf(v.w);
  }
#pragma unroll
  for (int off = 32; off; off >>= 1) s = fmaxf(s, __shfl_down(s, off));
  __shared__ float wmax[4];
  if ((t & 63) == 0) wmax[t >> 6] = s;
  __syncthreads();
  if (t == 0)
    sighi[mat] = sqrtf(fmaxf(fmaxf(wmax[0], wmax[1]), fmaxf(wmax[2], wmax[3])));
}

// ---------------- LDL inertia kernel v3: 8x8 tiles + padded conflict-free LDS ----------------
// counts[mat*NS + s] = #negative pivots of LDL^T(B - mu_s I) = #{lambda < mu_s}.
// The dumped pivot row lives ONLY in a padded layout: value at position p is
// vpad[(p>>3)*PAD + (p&7)]. Row reads (stride 8 positions) land on banks
// (10*rg+2j)%32 -> exactly 2-way over rg=0..31 (free). Col/pivot reads are
// half-wave/full-wave uniform broadcasts. Double-buffered on k parity.
__global__ __launch_bounds__(1024, 4) void ldl_kernel(const float* __restrict__ Ball,
                                                      const float* __restrict__ sighi,
                                                      int* __restrict__ counts) {
  const int s   = blockIdx.x;     // shift index 0..NS-1
  const int mat = blockIdx.y;     // 0..9
  const int t = threadIdx.x;      // 0..1023
  const int l = t & 63;
  const int w = t >> 6;              // wave 0..15
  const int rg = l & 31;             // row group: rows [8rg, 8rg+8)
  const int ch = 2 * w + (l >> 5);   // col chunk: cols [8ch, 8ch+8)
  const int r0 = rg << 3;
  const int c0 = ch << 3;

  __shared__ __align__(16) float vpad[2][32 * PAD];

  const float h = sighi[mat] * (1.f / NS);
  const float sg = (s + 1) * h;
  const float mu = sg * sg;

  float4 Bq[16];   // Bq[2i], Bq[2i+1] = row r0+i, cols c0..c0+7
  {
    const float* src = Ball + (size_t)mat * NW * NW + (size_t)r0 * NW + c0;
#pragma unroll
    for (int i = 0; i < 8; ++i) {
      Bq[2*i]     = *(const float4*)(src + i * NW);
      Bq[2*i + 1] = *(const float4*)(src + i * NW + 4);
    }
  }
  // diagonal tile: subtract mu at (r0+i, c0+i)
  if (r0 == c0) {
    Bq[0].x  -= mu; Bq[2].y  -= mu; Bq[4].z  -= mu; Bq[6].w  -= mu;
    Bq[9].x  -= mu; Bq[11].y -= mu; Bq[13].z -= mu; Bq[15].w -= mu;
  }

  // initial dump: column 0 = row 0 (symmetry), padded layout
  if (rg == 0) {
    float* vd = &vpad[0][ch * PAD];
    *(float2*)&vd[0] = make_float2(Bq[0].x, Bq[0].y);
    *(float2*)&vd[2] = make_float2(Bq[0].z, Bq[0].w);
    *(float2*)&vd[4] = make_float2(Bq[1].x, Bq[1].y);
    *(float2*)&vd[6] = make_float2(Bq[1].z, Bq[1].w);
  }
  __syncthreads();

  int cnt = 0;
  for (int k = 0; k < NW; ++k) {
    const float* vp = vpad[k & 1];
    const float d = vp[(k >> 3) * PAD + (k & 7)];   // pivot (uniform broadcast)
    cnt += (d < 0.f) ? 1 : 0;
    if (16 * w + 15 > k) {            // wave has live columns
      const float dg = (fabsf(d) < PIV_EPS) ? copysignf(PIV_EPS, d) : d;
      const float dinv = __builtin_amdgcn_rcpf(dg);
      // row values: 4x b64, 2-way banks (free)
      const float2 rv01 = *(const float2*)&vp[rg * PAD + 0];
      const float2 rv23 = *(const float2*)&vp[rg * PAD + 2];
      const float2 rv45 = *(const float2*)&vp[rg * PAD + 4];
      const float2 rv67 = *(const float2*)&vp[rg * PAD + 6];
      // col values: half-wave-uniform broadcasts
      const float2 cv01 = *(const float2*)&vp[ch * PAD + 0];
      const float2 cv23 = *(const float2*)&vp[ch * PAD + 2];
      const float2 cv45 = *(const float2*)&vp[ch * PAD + 4];
      const float2 cv67 = *(const float2*)&vp[ch * PAD + 6];
      const float rv[8] = {rv01.x, rv01.y, rv23.x, rv23.y, rv45.x, rv45.y, rv67.x, rv67.y};
      float f[8];
#pragma unroll
      for (int i = 0; i < 8; ++i)
        f[i] = (r0 + i > k) ? -rv[i] * dinv : 0.f;   // -L[r][k], masked rows
      const float4 cA = make_float4(cv01.x, cv01.y, cv23.x, cv23.y);
      const float4 cB = make_float4(cv45.x, cv45.y, cv67.x, cv67.y);
#pragma unroll
      for (int i = 0; i < 8; ++i) {
        Bq[2*i].x   = fmaf(f[i], cA.x, Bq[2*i].x);
        Bq[2*i].y   = fmaf(f[i], cA.y, Bq[2*i].y);
        Bq[2*i].z   = fmaf(f[i], cA.z, Bq[2*i].z);
        Bq[2*i].w   = fmaf(f[i], cA.w, Bq[2*i].w);
        Bq[2*i+1].x = fmaf(f[i], cB.x, Bq[2*i+1].x);
        Bq[2*i+1].y = fmaf(f[i], cB.y, Bq[2*i+1].y);
        Bq[2*i+1].z = fmaf(f[i], cB.z, Bq[2*i+1].z);
        Bq[2*i+1].w = fmaf(f[i], cB.w, Bq[2*i+1].w);
      }
      // dump updated row k+1 (= column k+1) into the other parity buffer.
      const int nr = k + 1;
      if (nr < NW && rg == (nr >> 3)) {
        float* vd = &vpad[nr & 1][ch * PAD];
        switch (nr & 7) {
          case 0: *(float2*)&vd[0] = make_float2(Bq[0].x,  Bq[0].y);
                  *(float2*)&vd[2] = make_float2(Bq[0].z,  Bq[0].w);
                  *(float2*)&vd[4] = make_float2(Bq[1].x,  Bq[1].y);
                  *(float2*)&vd[6] = make_float2(Bq[1].z,  Bq[1].w);  break;
          case 1: *(float2*)&vd[0] = make_float2(Bq[2].x,  Bq[2].y);
                  *(float2*)&vd[2] = make_float2(Bq[2].z,  Bq[2].w);
                  *(float2*)&vd[4] = make_float2(Bq[3].x,  Bq[3].y);
                  *(float2*)&vd[6] = make_float2(Bq[3].z,  Bq[3].w);  break;
          case 2: *(float2*)&vd[0] = make_float2(Bq[4].x,  Bq[4].y);
                  *(float2*)&vd[2] = make_float2(Bq[4].z,  Bq[4].w);
                  *(float2*)&vd[4] = make_float2(Bq[5].x,  Bq[5].y);
                  *(float2*)&vd[6] = make_float2(Bq[5].z,  Bq[5].w);  break;
          case 3: *(float2*)&vd[0] = make_float2(Bq[6].x,  Bq[6].y);
                  *(float2*)&vd[2] = make_float2(Bq[6].z,  Bq[6].w);
                  *(float2*)&vd[4] = make_float2(Bq[7].x,  Bq[7].y);
                  *(float2*)&vd[6] = make_float2(Bq[7].z,  Bq[7].w);  break;
          case 4: *(float2*)&vd[0] = make_float2(Bq[8].x,  Bq[8].y);
                  *(float2*)&vd[2] = make_float2(Bq[8].z,  Bq[8].w);
                  *(float2*)&vd[4] = make_float2(Bq[9].x,  Bq[9].y);
                  *(float2*)&vd[6] = make_float2(Bq[9].z,  Bq[9].w);  break;
          case 5: *(float2*)&vd[0] = make_float2(Bq[10].x, Bq[10].y);
                  *(float2*)&vd[2] = make_float2(Bq[10].z, Bq[10].w);
                  *(float2*)&vd[4] = make_float2(Bq[11].x, Bq[11].y);
                  *(float2*)&vd[6] = make_float2(Bq[11].z, Bq[11].w); break;
          case 6: *(float2*)&vd[0] = make_float2(Bq[12].x, Bq[12].y);
                  *(float2*)&vd[2] = make_float2(Bq[12].z, Bq[12].w);
                  *(float2*)&vd[4] = make_float2(Bq[13].x, Bq[13].y);
                  *(float2*)&vd[6] = make_float2(Bq[13].z, Bq[13].w); break;
          case 7: *(float2*)&vd[0] = make_float2(Bq[14].x, Bq[14].y);
                  *(float2*)&vd[2] = make_float2(Bq[14].z, Bq[14].w);
                  *(float2*)&vd[4] = make_float2(Bq[15].x, Bq[15].y);
                  *(float2*)&vd[6] = make_float2(Bq[15].z, Bq[15].w); break;
        }
      }
    }
    __syncthreads();
  }

  if (t == 0) counts[mat * NS + s] = cnt;
}

// ---------------- gather: bin each sorted eigenvalue from inertia counts ----------------
__global__ void gather_kernel(const int* __restrict__ counts, const float* __restrict__ sighi,
                              float* __restrict__ sigw) {
  const int mat = blockIdx.x;   // 10
  const int j = threadIdx.x;    // 256, ascending eigenvalue index
  __shared__ int cs[NS];
  if (j < NS) cs[j] = counts[mat * NS + j];
  __syncthreads();
  const float h = sighi[mat] * (1.f / NS);
  int cmax = 0;
  int sstar = NS - 1;
  bool found = false;
  for (int s = 0; s < NS; ++s) {
    cmax = max(cmax, cs[s]);              // enforce monotone counts
    if (!found && cmax > j) { sstar = s; found = true; }
  }
  // lambda_j in [mu_{s*-1}, mu_{s*}) -> sigma in [s*h, (s*+1)h)
  sigw[mat * NW + (255 - j)] = (sstar + 0.5f) * h;   // descending order
}

// ---------------- mean over blocks, broadcast over batch ----------------
__global__ void sig_avg_kernel(const float* __restrict__ sig, float* __restrict__ out_all) {
  const int b = blockIdx.x;   // 256
  const int j = threadIdx.x;  // 256
  float s = 0.f;
#pragma unroll
  for (int k = 0; k < NDEPTH; ++k) s += sig[k * NW + j];
  out_all[b * NW + j] = s * 0.1f;
}

extern "C" void kernel_launch(void* const* d_in, const int* in_sizes, int n_in,
                              void* d_out, int out_size, void* d_ws, size_t ws_size,
                              hipStream_t stream) {
  const float* x  = (const float*)d_in[0];
  const float* W1 = (const float*)d_in[1];
  const float* b1 = (const float*)d_in[2];
  const float* Wb = (const float*)d_in[3];
  const float* bb = (const float*)d_in[4];
  const float* Wl = (const float*)d_in[5];
  const float* bl = (const float*)d_in[6];
  float* out = (float*)d_out;               // 2560 + 65536

  float* ws = (float*)d_ws;
  float* Ball   = ws;                       // 10*65536 = 655360 floats
  float* sigw   = ws + 655360;              // 2560 floats
  float* sighiW = ws + 657920;              // 10 floats
  int*   counts = (int*)(ws + 657936);      // 10*NS ints

  bmat_kernel<<<dim3(NDEPTH * 32), dim3(256), 0, stream>>>(Wb, Ball);
  sighi_kernel<<<dim3(NDEPTH), dim3(256), 0, stream>>>(Ball, sighiW);
  forward_kernel<<<dim3(256), dim3(256), 0, stream>>>(x, W1, b1, Wb, bb, Wl, bl, out);
  ldl_kernel<<<dim3(NS, NDEPTH), dim3(1024), 0, stream>>>(Ball, sighiW, counts);
  gather_kernel<<<dim3(NDEPTH), dim3(256), 0, stream>>>(counts, sighiW, sigw);
  sig_avg_kernel<<<dim3(256), dim3(256), 0, stream>>>(sigw, out + 2560);
}

// Round 9
// 599.991 us; speedup vs baseline: 2.0486x; 1.2729x over previous
//
#include <hip/hip_runtime.h>
#include <hip/hip_bf16.h>

#define NW 256
#define NDEPTH 10
#define NS 56           // shifts per matrix (560 WGs ~ 2.2 rounds at 1 WG/CU)
#define PAD 10          // 8 floats padded to 10: gcd(10,32)=2 -> 2-way (free) conflicts
#define PIV_EPS 1e-6f   // LDL tiny-pivot guard

// ---------------- fused forward: first fc + 10 residual blocks + last fc ----------------
__global__ __launch_bounds__(256) void forward_kernel(
    const float* __restrict__ x, const float* __restrict__ W1, const float* __restrict__ b1,
    const float* __restrict__ Wb, const float* __restrict__ bb,
    const float* __restrict__ Wl, const float* __restrict__ bl,
    float* __restrict__ out) {
  const int b = blockIdx.x;
  const int o = threadIdx.x;
  __shared__ __align__(16) float xs[784];
  __shared__ __align__(16) float ybuf[2][NW];

  for (int k = o; k < 784; k += 256) xs[k] = x[(size_t)b * 784 + k];
  __syncthreads();

  {
    const float* w1r = W1 + (size_t)o * 784;
    float s = b1[o];
    for (int k = 0; k < 784; k += 4) {
      float4 w = *(const float4*)(w1r + k);
      float4 xv = *(const float4*)(&xs[k]);
      s += w.x * xv.x + w.y * xv.y + w.z * xv.z + w.w * xv.w;
    }
    ybuf[0][o] = fmaxf(s, 0.f);
  }
  __syncthreads();

  int cur = 0;
  for (int d = 0; d < NDEPTH; ++d) {
    const float* wr = Wb + (size_t)d * NW * NW + (size_t)o * NW;
    const float* yc = ybuf[cur];
    float acc = bb[d * NW + o];
#pragma unroll 8
    for (int k = 0; k < NW; k += 4) {
      float4 w = *(const float4*)(wr + k);
      float4 yv = *(const float4*)(&yc[k]);
      acc += w.x * yv.x + w.y * yv.y + w.z * yv.z + w.w * yv.w;
    }
    float ynew = fmaxf(acc, 0.f) + yc[o];
    ybuf[cur ^ 1][o] = ynew;
    __syncthreads();
    cur ^= 1;
  }

  if (o < 10) {
    const float* wr = Wl + o * NW;
    const float* yc = ybuf[cur];
    float acc = bl[o];
    for (int k = 0; k < NW; k += 4) {
      float4 w = *(const float4*)(wr + k);
      float4 yv = *(const float4*)(&yc[k]);
      acc += w.x * yv.x + w.y * yv.y + w.z * yv.z + w.w * yv.w;
    }
    out[b * 10 + o] = acc;
  }
}

// ---------------- B = (I+W)^T (I+W) for all 10 blocks ----------------
__global__ void bmat_kernel(const float* __restrict__ Wb, float* __restrict__ Ball) {
  const int blk = blockIdx.x;        // 10 * 32
  const int k   = blk >> 5;
  const int r0  = (blk & 31) << 3;   // 8 rows per block
  const int c   = threadIdx.x;       // 256
  const float* W = Wb + (size_t)k * NW * NW;
  float acc[8] = {0.f,0.f,0.f,0.f,0.f,0.f,0.f,0.f};
  for (int j = 0; j < NW; ++j) {
    const float wc = W[j * NW + c];
#pragma unroll
    for (int rr = 0; rr < 8; ++rr) acc[rr] += wc * W[j * NW + r0 + rr];
  }
#pragma unroll
  for (int rr = 0; rr < 8; ++rr) {
    const int r = r0 + rr;
    float s = acc[rr] + W[c * NW + r] + W[r * NW + c] + ((r == c) ? 1.f : 0.f);
    Ball[(size_t)k * NW * NW + r * NW + c] = s;
  }
}

// ---------------- sigma upper bound per matrix: sqrt(max abs row sum) ----------------
__global__ void sighi_kernel(const float* __restrict__ Ball, float* __restrict__ sighi) {
  const int mat = blockIdx.x;       // 10
  const int t = threadIdx.x;        // 256 (one row each)
  const float* row = Ball + (size_t)mat * NW * NW + (size_t)t * NW;
  float s = 0.f;
  for (int c = 0; c < NW; c += 4) {
    const float4 v = *(const float4*)(row + c);
    s += fabsf(v.x) + fabsf(v.y) + fabsf(v.z) + fabsf(v.w);
  }
#pragma unroll
  for (int off = 32; off; off >>= 1) s = fmaxf(s, __shfl_down(s, off));
  __shared__ float wmax[4];
  if ((t & 63) == 0) wmax[t >> 6] = s;
  __syncthreads();
  if (t == 0)
    sighi[mat] = sqrtf(fmaxf(fmaxf(wmax[0], wmax[1]), fmaxf(wmax[2], wmax[3])));
}

// ---------------- LDL inertia kernel v4: rank-2 pivots per barrier ----------------
// counts[mat*NS + s] = #negative pivots of LDL^T(B - mu_s I) = #{lambda < mu_s}.
// Super-iteration m handles pivots k=2m, k+1. Rows k,k+1 (= columns by symmetry)
// live in padded LDS (double-buffered by m-parity). Per thread: 2x2 pivot chain
// from 3 uniform reads; folded rank-2 update (f0 - l10*f1)*cv0 + f1*cv1 on its
// 8x8 register tile; single barrier per 2 pivots. One owner thread per chunk
// dumps BOTH rows k+2,k+3 (same row-group since k is even).
__global__ __launch_bounds__(1024, 4) void ldl_kernel(const float* __restrict__ Ball,
                                                      const float* __restrict__ sighi,
                                                      int* __restrict__ counts) {
  const int s   = blockIdx.x;     // shift index 0..NS-1
  const int mat = blockIdx.y;     // 0..9
  const int t = threadIdx.x;      // 0..1023
  const int l = t & 63;
  const int w = t >> 6;              // wave 0..15
  const int rg = l & 31;             // row group: rows [8rg, 8rg+8)
  const int ch = 2 * w + (l >> 5);   // col chunk: cols [8ch, 8ch+8)
  const int r0 = rg << 3;

  __shared__ __align__(16) float vrow[2][2][32 * PAD];   // [m-parity][row k+0/k+1]

  const float h = sighi[mat] * (1.f / NS);
  const float sg = (s + 1) * h;
  const float mu = sg * sg;

  float Bf[64];   // row r0+i, col c0+j at Bf[i*8+j]
  {
    const float* src = Ball + (size_t)mat * NW * NW + (size_t)r0 * NW + (ch << 3);
#pragma unroll
    for (int i = 0; i < 8; ++i) {
      const float4 a = *(const float4*)(src + i * NW);
      const float4 b = *(const float4*)(src + i * NW + 4);
      Bf[i*8+0] = a.x; Bf[i*8+1] = a.y; Bf[i*8+2] = a.z; Bf[i*8+3] = a.w;
      Bf[i*8+4] = b.x; Bf[i*8+5] = b.y; Bf[i*8+6] = b.z; Bf[i*8+7] = b.w;
    }
  }
  // diagonal tile: subtract mu at (r0+i, c0+i)
  if (rg == ch) {
#pragma unroll
    for (int i = 0; i < 8; ++i) Bf[i*8+i] -= mu;
  }

  // initial dump: rows 0 and 1 (= columns 0,1), padded layout, parity 0
  if (rg == 0) {
    float* vd0 = &vrow[0][0][ch * PAD];
    float* vd1 = &vrow[0][1][ch * PAD];
#pragma unroll
    for (int j = 0; j < 8; j += 2) {
      *(float2*)&vd0[j] = make_float2(Bf[j],     Bf[j + 1]);
      *(float2*)&vd1[j] = make_float2(Bf[8 + j], Bf[8 + j + 1]);
    }
  }
  __syncthreads();

  int cnt = 0;
  for (int m = 0; m < NW / 2; ++m) {
    const int k = 2 * m;
    const int par = m & 1;
    const float* v0 = vrow[par][0];
    const float* v1 = vrow[par][1];

    // ---- 2x2 pivot chain from uniform reads (all threads, for cnt) ----
    const float d0  = v0[((k) >> 3) * PAD + (k & 7)];
    const float u01 = v0[((k + 1) >> 3) * PAD + ((k + 1) & 7)];
    const float e1  = v1[((k + 1) >> 3) * PAD + ((k + 1) & 7)];
    const float d0g = (fabsf(d0) < PIV_EPS) ? copysignf(PIV_EPS, d0) : d0;
    const float i0  = __builtin_amdgcn_rcpf(d0g);
    const float l10 = u01 * i0;
    const float d1  = e1 - l10 * u01;
    const float d1g = (fabsf(d1) < PIV_EPS) ? copysignf(PIV_EPS, d1) : d1;
    const float i1  = __builtin_amdgcn_rcpf(d1g);
    cnt += (d0 < 0.f) ? 1 : 0;
    cnt += (d1 < 0.f) ? 1 : 0;

    if (16 * w + 15 > k) {            // wave has live columns
      // row values for rows [r0, r0+8): 8x b64 padded (2-way banks, free)
      const float2 a01 = *(const float2*)&v0[rg * PAD + 0];
      const float2 a23 = *(const float2*)&v0[rg * PAD + 2];
      const float2 a45 = *(const float2*)&v0[rg * PAD + 4];
      const float2 a67 = *(const float2*)&v0[rg * PAD + 6];
      const float2 b01 = *(const float2*)&v1[rg * PAD + 0];
      const float2 b23 = *(const float2*)&v1[rg * PAD + 2];
      const float2 b45 = *(const float2*)&v1[rg * PAD + 4];
      const float2 b67 = *(const float2*)&v1[rg * PAD + 6];
      const float rv0[8] = {a01.x, a01.y, a23.x, a23.y, a45.x, a45.y, a67.x, a67.y};
      const float rv1[8] = {b01.x, b01.y, b23.x, b23.y, b45.x, b45.y, b67.x, b67.y};
      // col values: half-wave-uniform broadcasts
      const float2 c01 = *(const float2*)&v0[ch * PAD + 0];
      const float2 c23 = *(const float2*)&v0[ch * PAD + 2];
      const float2 c45 = *(const float2*)&v0[ch * PAD + 4];
      const float2 c67 = *(const float2*)&v0[ch * PAD + 6];
      const float2 d01 = *(const float2*)&v1[ch * PAD + 0];
      const float2 d23 = *(const float2*)&v1[ch * PAD + 2];
      const float2 d45 = *(const float2*)&v1[ch * PAD + 4];
      const float2 d67 = *(const float2*)&v1[ch * PAD + 6];
      const float cv0[8] = {c01.x, c01.y, c23.x, c23.y, c45.x, c45.y, c67.x, c67.y};
      const float cv1[8] = {d01.x, d01.y, d23.x, d23.y, d45.x, d45.y, d67.x, d67.y};

      // factors: f0 = -L0[r], f1 = -L1[r]; folded g0 = f0 - l10*f1
      float g0[8], f1[8];
#pragma unroll
      for (int i = 0; i < 8; ++i) {
        const int r = r0 + i;
        const float f0 = (r > k)     ? -rv0[i] * i0 : 0.f;
        const float v1p = rv1[i] - l10 * rv0[i];   // updated column k+1 at row r
        f1[i] = (r > k + 1) ? -v1p * i1 : 0.f;
        g0[i] = f0 - l10 * f1[i];
      }
      // rank-2 update: B += g0*cv0^T + f1*cv1^T
#pragma unroll
      for (int i = 0; i < 8; ++i) {
#pragma unroll
        for (int j = 0; j < 8; ++j) {
          Bf[i*8+j] = fmaf(g0[i], cv0[j], fmaf(f1[i], cv1[j], Bf[i*8+j]));
        }
      }
      // dump rows k+2, k+3 (same owner row-group since k is even)
      const int nr = k + 2;
      if (nr < NW && rg == (nr >> 3)) {
        float* vd0 = &vrow[par ^ 1][0][ch * PAD];
        float* vd1 = &vrow[par ^ 1][1][ch * PAD];
        const int i0r = (nr & 7) * 8;     // scalar-uniform: (nr&6)*8 with nr even
        switch (nr & 7) {
          case 0:
#pragma unroll
            for (int j = 0; j < 8; j += 2) {
              *(float2*)&vd0[j] = make_float2(Bf[0*8+j], Bf[0*8+j+1]);
              *(float2*)&vd1[j] = make_float2(Bf[1*8+j], Bf[1*8+j+1]);
            } break;
          case 2:
#pragma unroll
            for (int j = 0; j < 8; j += 2) {
              *(float2*)&vd0[j] = make_float2(Bf[2*8+j], Bf[2*8+j+1]);
              *(float2*)&vd1[j] = make_float2(Bf[3*8+j], Bf[3*8+j+1]);
            } break;
          case 4:
#pragma unroll
            for (int j = 0; j < 8; j += 2) {
              *(float2*)&vd0[j] = make_float2(Bf[4*8+j], Bf[4*8+j+1]);
              *(float2*)&vd1[j] = make_float2(Bf[5*8+j], Bf[5*8+j+1]);
            } break;
          default:  // case 6
#pragma unroll
            for (int j = 0; j < 8; j += 2) {
              *(float2*)&vd0[j] = make_float2(Bf[6*8+j], Bf[6*8+j+1]);
              *(float2*)&vd1[j] = make_float2(Bf[7*8+j], Bf[7*8+j+1]);
            } break;
        }
        (void)i0r;
      }
    }
    __syncthreads();
  }

  if (t == 0) counts[mat * NS + s] = cnt;
}

// ---------------- gather: bin each sorted eigenvalue from inertia counts ----------------
__global__ void gather_kernel(const int* __restrict__ counts, const float* __restrict__ sighi,
                              float* __restrict__ sigw) {
  const int mat = blockIdx.x;   // 10
  const int j = threadIdx.x;    // 256, ascending eigenvalue index
  __shared__ int cs[NS];
  if (j < NS) cs[j] = counts[mat * NS + j];
  __syncthreads();
  const float h = sighi[mat] * (1.f / NS);
  int cmax = 0;
  int sstar = NS - 1;
  bool found = false;
  for (int s = 0; s < NS; ++s) {
    cmax = max(cmax, cs[s]);              // enforce monotone counts
    if (!found && cmax > j) { sstar = s; found = true; }
  }
  // lambda_j in [mu_{s*-1}, mu_{s*}) -> sigma in [s*h, (s*+1)h)
  sigw[mat * NW + (255 - j)] = (sstar + 0.5f) * h;   // descending order
}

// ---------------- mean over blocks, broadcast over batch ----------------
__global__ void sig_avg_kernel(const float* __restrict__ sig, float* __restrict__ out_all) {
  const int b = blockIdx.x;   // 256
  const int j = threadIdx.x;  // 256
  float s = 0.f;
#pragma unroll
  for (int k = 0; k < NDEPTH; ++k) s += sig[k * NW + j];
  out_all[b * NW + j] = s * 0.1f;
}

extern "C" void kernel_launch(void* const* d_in, const int* in_sizes, int n_in,
                              void* d_out, int out_size, void* d_ws, size_t ws_size,
                              hipStream_t stream) {
  const float* x  = (const float*)d_in[0];
  const float* W1 = (const float*)d_in[1];
  const float* b1 = (const float*)d_in[2];
  const float* Wb = (const float*)d_in[3];
  const float* bb = (const float*)d_in[4];
  const float* Wl = (const float*)d_in[5];
  const float* bl = (const float*)d_in[6];
  float* out = (float*)d_out;               // 2560 + 65536

  float* ws = (float*)d_ws;
  float* Ball   = ws;                       // 10*65536 = 655360 floats
  float* sigw   = ws + 655360;              // 2560 floats
  float* sighiW = ws + 657920;              // 10 floats
  int*   counts = (int*)(ws + 657936);      // 10*NS ints

  bmat_kernel<<<dim3(NDEPTH * 32), dim3(256), 0, stream>>>(Wb, Ball);
  sighi_kernel<<<dim3(NDEPTH), dim3(256), 0, stream>>>(Ball, sighiW);
  forward_kernel<<<dim3(256), dim3(256), 0, stream>>>(x, W1, b1, Wb, bb, Wl, bl, out);
  ldl_kernel<<<dim3(NS, NDEPTH), dim3(1024), 0, stream>>>(Ball, sighiW, counts);
  gather_kernel<<<dim3(NDEPTH), dim3(256), 0, stream>>>(counts, sighiW, sigw);
  sig_avg_kernel<<<dim3(256), dim3(256), 0, stream>>>(sigw, out + 2560);
}

// Round 10
// 440.348 us; speedup vs baseline: 2.7912x; 1.3625x over previous
//
#include <hip/hip_runtime.h>
#include <hip/hip_bf16.h>

#define NW 256
#define NDEPTH 10
#define NS 51           // shifts per matrix: 510 WGs = exactly 2 rounds at 1 WG/CU
#define PAD 12          // stride 48B: 16B-aligned rows, bank-group 3rg%8 injective
#define PIV_EPS 1e-6f   // LDL tiny-pivot guard

// ---------------- fused forward: first fc + 10 residual blocks + last fc ----------------
__global__ __launch_bounds__(256) void forward_kernel(
    const float* __restrict__ x, const float* __restrict__ W1, const float* __restrict__ b1,
    const float* __restrict__ Wb, const float* __restrict__ bb,
    const float* __restrict__ Wl, const float* __restrict__ bl,
    float* __restrict__ out) {
  const int b = blockIdx.x;
  const int o = threadIdx.x;
  __shared__ __align__(16) float xs[784];
  __shared__ __align__(16) float ybuf[2][NW];

  for (int k = o; k < 784; k += 256) xs[k] = x[(size_t)b * 784 + k];
  __syncthreads();

  {
    const float* w1r = W1 + (size_t)o * 784;
    float s = b1[o];
    for (int k = 0; k < 784; k += 4) {
      float4 w = *(const float4*)(w1r + k);
      float4 xv = *(const float4*)(&xs[k]);
      s += w.x * xv.x + w.y * xv.y + w.z * xv.z + w.w * xv.w;
    }
    ybuf[0][o] = fmaxf(s, 0.f);
  }
  __syncthreads();

  int cur = 0;
  for (int d = 0; d < NDEPTH; ++d) {
    const float* wr = Wb + (size_t)d * NW * NW + (size_t)o * NW;
    const float* yc = ybuf[cur];
    float acc = bb[d * NW + o];
#pragma unroll 8
    for (int k = 0; k < NW; k += 4) {
      float4 w = *(const float4*)(wr + k);
      float4 yv = *(const float4*)(&yc[k]);
      acc += w.x * yv.x + w.y * yv.y + w.z * yv.z + w.w * yv.w;
    }
    float ynew = fmaxf(acc, 0.f) + yc[o];
    ybuf[cur ^ 1][o] = ynew;
    __syncthreads();
    cur ^= 1;
  }

  if (o < 10) {
    const float* wr = Wl + o * NW;
    const float* yc = ybuf[cur];
    float acc = bl[o];
    for (int k = 0; k < NW; k += 4) {
      float4 w = *(const float4*)(wr + k);
      float4 yv = *(const float4*)(&yc[k]);
      acc += w.x * yv.x + w.y * yv.y + w.z * yv.z + w.w * yv.w;
    }
    out[b * 10 + o] = acc;
  }
}

// ---------------- B = (I+W)^T (I+W) for all 10 blocks ----------------
__global__ void bmat_kernel(const float* __restrict__ Wb, float* __restrict__ Ball) {
  const int blk = blockIdx.x;        // 10 * 32
  const int k   = blk >> 5;
  const int r0  = (blk & 31) << 3;   // 8 rows per block
  const int c   = threadIdx.x;       // 256
  const float* W = Wb + (size_t)k * NW * NW;
  float acc[8] = {0.f,0.f,0.f,0.f,0.f,0.f,0.f,0.f};
  for (int j = 0; j < NW; ++j) {
    const float wc = W[j * NW + c];
#pragma unroll
    for (int rr = 0; rr < 8; ++rr) acc[rr] += wc * W[j * NW + r0 + rr];
  }
#pragma unroll
  for (int rr = 0; rr < 8; ++rr) {
    const int r = r0 + rr;
    float s = acc[rr] + W[c * NW + r] + W[r * NW + c] + ((r == c) ? 1.f : 0.f);
    Ball[(size_t)k * NW * NW + r * NW + c] = s;
  }
}

// ---------------- sigma upper bound per matrix: sqrt(max abs row sum) ----------------
__global__ void sighi_kernel(const float* __restrict__ Ball, float* __restrict__ sighi) {
  const int mat = blockIdx.x;       // 10
  const int t = threadIdx.x;        // 256 (one row each)
  const float* row = Ball + (size_t)mat * NW * NW + (size_t)t * NW;
  float s = 0.f;
  for (int c = 0; c < NW; c += 4) {
    const float4 v = *(const float4*)(row + c);
    s += fabsf(v.x) + fabsf(v.y) + fabsf(v.z) + fabsf(v.w);
  }
#pragma unroll
  for (int off = 32; off; off >>= 1) s = fmaxf(s, __shfl_down(s, off));
  __shared__ float wmax[4];
  if ((t & 63) == 0) wmax[t >> 6] = s;
  __syncthreads();
  if (t == 0)
    sighi[mat] = sqrtf(fmaxf(fmaxf(wmax[0], wmax[1]), fmaxf(wmax[2], wmax[3])));
}

// ---------------- LDL inertia kernel v5: rank-2 + b128 LDS ops ----------------
// counts[mat*NS + s] = #negative pivots of LDL^T(B - mu_s I) = #{lambda < mu_s}.
// PAD=12 floats (48B): every row slice 16B-aligned -> ds_read_b128 for row/col
// values (4+4 instrs), pivot pair = 1 b64 + 1 b32. 10 LDS instrs/wave/iter
// (was 19). Bank-group of row reads = 3rg%8, injective mod 8 (b128 floor).
__global__ __launch_bounds__(1024, 4) void ldl_kernel(const float* __restrict__ Ball,
                                                      const float* __restrict__ sighi,
                                                      int* __restrict__ counts) {
  const int s   = blockIdx.x;     // shift index 0..NS-1
  const int mat = blockIdx.y;     // 0..9
  const int t = threadIdx.x;      // 0..1023
  const int l = t & 63;
  const int w = t >> 6;              // wave 0..15
  const int rg = l & 31;             // row group: rows [8rg, 8rg+8)
  const int ch = 2 * w + (l >> 5);   // col chunk: cols [8ch, 8ch+8)
  const int r0 = rg << 3;

  __shared__ __align__(16) float vrow[2][2][32 * PAD];   // [m-parity][row k+0/k+1]

  const float h = sighi[mat] * (1.f / NS);
  const float sg = (s + 1) * h;
  const float mu = sg * sg;

  float Bf[64];   // row r0+i, col c0+j at Bf[i*8+j]
  {
    const float* src = Ball + (size_t)mat * NW * NW + (size_t)r0 * NW + (ch << 3);
#pragma unroll
    for (int i = 0; i < 8; ++i) {
      const float4 a = *(const float4*)(src + i * NW);
      const float4 b = *(const float4*)(src + i * NW + 4);
      Bf[i*8+0] = a.x; Bf[i*8+1] = a.y; Bf[i*8+2] = a.z; Bf[i*8+3] = a.w;
      Bf[i*8+4] = b.x; Bf[i*8+5] = b.y; Bf[i*8+6] = b.z; Bf[i*8+7] = b.w;
    }
  }
  // diagonal tile: subtract mu at (r0+i, c0+i)
  if (rg == ch) {
#pragma unroll
    for (int i = 0; i < 8; ++i) Bf[i*8+i] -= mu;
  }

  // initial dump: rows 0 and 1 (= columns 0,1), parity 0
  if (rg == 0) {
    float* vd0 = &vrow[0][0][ch * PAD];
    float* vd1 = &vrow[0][1][ch * PAD];
    *(float4*)&vd0[0] = make_float4(Bf[0],  Bf[1],  Bf[2],  Bf[3]);
    *(float4*)&vd0[4] = make_float4(Bf[4],  Bf[5],  Bf[6],  Bf[7]);
    *(float4*)&vd1[0] = make_float4(Bf[8],  Bf[9],  Bf[10], Bf[11]);
    *(float4*)&vd1[4] = make_float4(Bf[12], Bf[13], Bf[14], Bf[15]);
  }
  __syncthreads();

  int cnt = 0;
  for (int m = 0; m < NW / 2; ++m) {
    const int k = 2 * m;
    const int par = m & 1;
    const float* v0 = vrow[par][0];
    const float* v1 = vrow[par][1];

    // ---- 2x2 pivot chain: one b64 + one b32 uniform read ----
    const int kpos = (k >> 3) * PAD + (k & 7);      // k even -> 8B-aligned
    const float2 p01 = *(const float2*)&v0[kpos];
    const float d0  = p01.x;
    const float u01 = p01.y;
    const float e1  = v1[kpos + 1];
    const float d0g = (fabsf(d0) < PIV_EPS) ? copysignf(PIV_EPS, d0) : d0;
    const float i0  = __builtin_amdgcn_rcpf(d0g);
    const float l10 = u01 * i0;
    const float d1  = e1 - l10 * u01;
    const float d1g = (fabsf(d1) < PIV_EPS) ? copysignf(PIV_EPS, d1) : d1;
    const float i1  = __builtin_amdgcn_rcpf(d1g);
    cnt += (d0 < 0.f) ? 1 : 0;
    cnt += (d1 < 0.f) ? 1 : 0;

    if (16 * w + 15 > k) {            // wave has live columns
      // row values: 4x b128 (16B-aligned, bank-group injective)
      const float4 ra0 = *(const float4*)&v0[rg * PAD + 0];
      const float4 ra1 = *(const float4*)&v0[rg * PAD + 4];
      const float4 rb0 = *(const float4*)&v1[rg * PAD + 0];
      const float4 rb1 = *(const float4*)&v1[rg * PAD + 4];
      // col values: 4x b128 uniform broadcasts (per half-wave)
      const float4 ca0 = *(const float4*)&v0[ch * PAD + 0];
      const float4 ca1 = *(const float4*)&v0[ch * PAD + 4];
      const float4 cb0 = *(const float4*)&v1[ch * PAD + 0];
      const float4 cb1 = *(const float4*)&v1[ch * PAD + 4];
      const float rv0[8] = {ra0.x, ra0.y, ra0.z, ra0.w, ra1.x, ra1.y, ra1.z, ra1.w};
      const float rv1[8] = {rb0.x, rb0.y, rb0.z, rb0.w, rb1.x, rb1.y, rb1.z, rb1.w};
      const float cv0[8] = {ca0.x, ca0.y, ca0.z, ca0.w, ca1.x, ca1.y, ca1.z, ca1.w};
      const float cv1[8] = {cb0.x, cb0.y, cb0.z, cb0.w, cb1.x, cb1.y, cb1.z, cb1.w};

      // factors: f0 = -L0[r], f1 = -L1[r]; folded g0 = f0 - l10*f1
      float g0[8], f1[8];
#pragma unroll
      for (int i = 0; i < 8; ++i) {
        const int r = r0 + i;
        const float f0 = (r > k)     ? -rv0[i] * i0 : 0.f;
        const float v1p = rv1[i] - l10 * rv0[i];   // updated column k+1 at row r
        f1[i] = (r > k + 1) ? -v1p * i1 : 0.f;
        g0[i] = f0 - l10 * f1[i];
      }
      // rank-2 update: B += g0*cv0^T + f1*cv1^T
#pragma unroll
      for (int i = 0; i < 8; ++i) {
#pragma unroll
        for (int j = 0; j < 8; ++j) {
          Bf[i*8+j] = fmaf(g0[i], cv0[j], fmaf(f1[i], cv1[j], Bf[i*8+j]));
        }
      }
      // dump rows k+2, k+3 (same owner row-group since k is even)
      const int nr = k + 2;
      if (nr < NW && rg == (nr >> 3)) {
        float* vd0 = &vrow[par ^ 1][0][ch * PAD];
        float* vd1 = &vrow[par ^ 1][1][ch * PAD];
        switch (nr & 7) {
          case 0:
            *(float4*)&vd0[0] = make_float4(Bf[0],  Bf[1],  Bf[2],  Bf[3]);
            *(float4*)&vd0[4] = make_float4(Bf[4],  Bf[5],  Bf[6],  Bf[7]);
            *(float4*)&vd1[0] = make_float4(Bf[8],  Bf[9],  Bf[10], Bf[11]);
            *(float4*)&vd1[4] = make_float4(Bf[12], Bf[13], Bf[14], Bf[15]);
            break;
          case 2:
            *(float4*)&vd0[0] = make_float4(Bf[16], Bf[17], Bf[18], Bf[19]);
            *(float4*)&vd0[4] = make_float4(Bf[20], Bf[21], Bf[22], Bf[23]);
            *(float4*)&vd1[0] = make_float4(Bf[24], Bf[25], Bf[26], Bf[27]);
            *(float4*)&vd1[4] = make_float4(Bf[28], Bf[29], Bf[30], Bf[31]);
            break;
          case 4:
            *(float4*)&vd0[0] = make_float4(Bf[32], Bf[33], Bf[34], Bf[35]);
            *(float4*)&vd0[4] = make_float4(Bf[36], Bf[37], Bf[38], Bf[39]);
            *(float4*)&vd1[0] = make_float4(Bf[40], Bf[41], Bf[42], Bf[43]);
            *(float4*)&vd1[4] = make_float4(Bf[44], Bf[45], Bf[46], Bf[47]);
            break;
          default:  // case 6
            *(float4*)&vd0[0] = make_float4(Bf[48], Bf[49], Bf[50], Bf[51]);
            *(float4*)&vd0[4] = make_float4(Bf[52], Bf[53], Bf[54], Bf[55]);
            *(float4*)&vd1[0] = make_float4(Bf[56], Bf[57], Bf[58], Bf[59]);
            *(float4*)&vd1[4] = make_float4(Bf[60], Bf[61], Bf[62], Bf[63]);
            break;
        }
      }
    }
    __syncthreads();
  }

  if (t == 0) counts[mat * NS + s] = cnt;
}

// ---------------- gather: bin each sorted eigenvalue from inertia counts ----------------
__global__ void gather_kernel(const int* __restrict__ counts, const float* __restrict__ sighi,
                              float* __restrict__ sigw) {
  const int mat = blockIdx.x;   // 10
  const int j = threadIdx.x;    // 256, ascending eigenvalue index
  __shared__ int cs[NS];
  if (j < NS) cs[j] = counts[mat * NS + j];
  __syncthreads();
  const float h = sighi[mat] * (1.f / NS);
  int cmax = 0;
  int sstar = NS - 1;
  bool found = false;
  for (int s = 0; s < NS; ++s) {
    cmax = max(cmax, cs[s]);              // enforce monotone counts
    if (!found && cmax > j) { sstar = s; found = true; }
  }
  // lambda_j in [mu_{s*-1}, mu_{s*}) -> sigma in [s*h, (s*+1)h)
  sigw[mat * NW + (255 - j)] = (sstar + 0.5f) * h;   // descending order
}

// ---------------- mean over blocks, broadcast over batch ----------------
__global__ void sig_avg_kernel(const float* __restrict__ sig, float* __restrict__ out_all) {
  const int b = blockIdx.x;   // 256
  const int j = threadIdx.x;  // 256
  float s = 0.f;
#pragma unroll
  for (int k = 0; k < NDEPTH; ++k) s += sig[k * NW + j];
  out_all[b * NW + j] = s * 0.1f;
}

extern "C" void kernel_launch(void* const* d_in, const int* in_sizes, int n_in,
                              void* d_out, int out_size, void* d_ws, size_t ws_size,
                              hipStream_t stream) {
  const float* x  = (const float*)d_in[0];
  const float* W1 = (const float*)d_in[1];
  const float* b1 = (const float*)d_in[2];
  const float* Wb = (const float*)d_in[3];
  const float* bb = (const float*)d_in[4];
  const float* Wl = (const float*)d_in[5];
  const float* bl = (const float*)d_in[6];
  float* out = (float*)d_out;               // 2560 + 65536

  float* ws = (float*)d_ws;
  float* Ball   = ws;                       // 10*65536 = 655360 floats
  float* sigw   = ws + 655360;              // 2560 floats
  float* sighiW = ws + 657920;              // 10 floats
  int*   counts = (int*)(ws + 657936);      // 10*NS ints

  bmat_kernel<<<dim3(NDEPTH * 32), dim3(256), 0, stream>>>(Wb, Ball);
  sighi_kernel<<<dim3(NDEPTH), dim3(256), 0, stream>>>(Ball, sighiW);
  forward_kernel<<<dim3(256), dim3(256), 0, stream>>>(x, W1, b1, Wb, bb, Wl, bl, out);
  ldl_kernel<<<dim3(NS, NDEPTH), dim3(1024), 0, stream>>>(Ball, sighiW, counts);
  gather_kernel<<<dim3(NDEPTH), dim3(256), 0, stream>>>(counts, sighiW, sigw);
  sig_avg_kernel<<<dim3(256), dim3(256), 0, stream>>>(sigw, out + 2560);
}